// Round 3
// baseline (169.706 us; speedup 1.0000x reference)
//
#include <hip/hip_runtime.h>

#define NN 8192
#define MM 8192
#define DD 256
#define NPART 8
#define MPART (MM / NPART)   // 1024
#define BK 32
#define NT (MPART / BK)      // 32

typedef short bf16x8 __attribute__((ext_vector_type(8)));
typedef short bf16x4 __attribute__((ext_vector_type(4)));
typedef float f32x4 __attribute__((ext_vector_type(4)));
typedef unsigned int u32;
typedef u32 u32x4 __attribute__((ext_vector_type(4)));

#define GLL16(src, dst) __builtin_amdgcn_global_load_lds( \
    (__attribute__((address_space(1))) void*)(src), \
    (__attribute__((address_space(3))) void*)(dst), 16, 0, 0)

static __device__ __forceinline__ short f2bf(float f) {
    unsigned u = __float_as_uint(f);
    u += 0x7fffu + ((u >> 16) & 1u);   // RNE
    return (short)(u >> 16);
}

static __device__ __forceinline__ u32 cvtpk(float lo, float hi) {
    u32 r;
    asm("v_cvt_pk_bf16_f32 %0, %1, %2" : "=v"(r) : "v"(lo), "v"(hi));
    return r;
}

// ---------------- projection: y = x @ W^T + b  -> bf16 ----------------
__global__ __launch_bounds__(256, 2) void proj_kernel(
    const float* __restrict__ xq, const float* __restrict__ xkv,
    const float* __restrict__ Wq, const float* __restrict__ bq,
    const float* __restrict__ Wk, const float* __restrict__ bk,
    const float* __restrict__ Wv, const float* __restrict__ bv,
    short* __restrict__ qo, short* __restrict__ ko, short* __restrict__ vTo)
{
    __shared__ short Xs[64][264];
    __shared__ short Ws[64][264];

    const int bid = blockIdx.x;
    const int mat = bid >> 9;
    const int t = bid & 511;
    const int rt = t >> 2;
    const int ct = t & 3;
    const float* __restrict__ X = (mat == 0) ? xq : xkv;
    const float* __restrict__ W = (mat == 0) ? Wq : ((mat == 1) ? Wk : Wv);
    const float* __restrict__ bias = (mat == 0) ? bq : ((mat == 1) ? bk : bv);

    const int tid = threadIdx.x;
    const int lane = tid & 63;
    const int wv = tid >> 6;
    const int l15 = lane & 15;
    const int lg = lane >> 4;

    #pragma unroll
    for (int i = 0; i < 16; ++i) {
        int c = i * 256 + tid;
        int row = c >> 6;
        int col4 = (c & 63) << 2;
        f32x4 xv = *reinterpret_cast<const f32x4*>(X + (size_t)(rt * 64 + row) * DD + col4);
        f32x4 wr = *reinterpret_cast<const f32x4*>(W + (size_t)(ct * 64 + row) * DD + col4);
        bf16x4 xb, wb;
        #pragma unroll
        for (int j = 0; j < 4; ++j) { xb[j] = f2bf(xv[j]); wb[j] = f2bf(wr[j]); }
        *reinterpret_cast<bf16x4*>(&Xs[row][col4]) = xb;
        *reinterpret_cast<bf16x4*>(&Ws[row][col4]) = wb;
    }
    __syncthreads();

    f32x4 acc[4];
    #pragma unroll
    for (int f = 0; f < 4; ++f) acc[f] = f32x4{0.f, 0.f, 0.f, 0.f};

    #pragma unroll
    for (int kk = 0; kk < 8; ++kk) {
        bf16x8 a = *reinterpret_cast<const bf16x8*>(&Xs[wv * 16 + l15][kk * 32 + lg * 8]);
        #pragma unroll
        for (int f = 0; f < 4; ++f) {
            bf16x8 b = *reinterpret_cast<const bf16x8*>(&Ws[f * 16 + l15][kk * 32 + lg * 8]);
            acc[f] = __builtin_amdgcn_mfma_f32_16x16x32_bf16(a, b, acc[f], 0, 0, 0);
        }
    }

    #pragma unroll
    for (int f = 0; f < 4; ++f) {
        const int o = ct * 64 + f * 16 + l15;
        const float bsv = bias[o];
        if (mat == 2) {
            bf16x4 pk;
            #pragma unroll
            for (int r = 0; r < 4; ++r) pk[r] = f2bf(acc[f][r] + bsv);
            const int mb = rt * 64 + wv * 16 + lg * 4;
            *reinterpret_cast<bf16x4*>(&vTo[(size_t)o * MM + mb]) = pk;
        } else {
            // q: fold 1/sqrt(D)=1/16 and log2(e) (softmax in exp2 domain)
            const float sc = (mat == 0) ? 0.0625f * 1.44269504089f : 1.0f;
            short* __restrict__ dst = (mat == 0) ? qo : ko;
            #pragma unroll
            for (int r = 0; r < 4; ++r) {
                const int rowg = rt * 64 + wv * 16 + lg * 4 + r;
                dst[(size_t)rowg * DD + o] = f2bf((acc[f][r] + bsv) * sc);
            }
        }
    }
}

// ---------------- flash attention, swapped-operand structure ----------------
// grid: 512 = 64 q-tiles(128 rows) x 8 parts; 256 threads (4 waves x 32 q-rows)
// S^T = K·Q^T and O^T = V^T·P : softmax q-index is lane-local (q = lane&15),
// P redistributed in-register (cvt_pk + shfl), no P-LDS, lane-local rescale.
__global__ __launch_bounds__(256, 2) void attn_kernel(
    const short* __restrict__ qg, const short* __restrict__ kg,
    const short* __restrict__ vT, float* __restrict__ outp,
    float* __restrict__ statm, float* __restrict__ statl)
{
    __shared__ short Ks[2][BK * DD];   // 16KB each; row 512B, chunk c holds logical c^(row&7)
    __shared__ short Vs[2][DD * BK];   // 16KB each; granule-major: g*4KB + ((d^2g)*16B)
    __shared__ float Tp[4][16 * 20];   // per-wave transpose patch (rows padded to 80B)

    const int bid = blockIdx.x;
    const int p = bid & 7;             // XCD-pinned part
    const int qt = bid >> 3;
    const int q0 = qt * 128;
    const int m0base = p * MPART;

    const int tid = threadIdx.x;
    const int lane = tid & 63;
    const int w = tid >> 6;
    const int wu = __builtin_amdgcn_readfirstlane(w);
    const int l15 = lane & 15;
    const int lg = lane >> 4;

    // Q as B-fragments: qf[qh][kk] = Q[q0+w*32+qh*16+l15][kk*32+lg*8 ..+7]
    bf16x8 qf[2][8];
    #pragma unroll
    for (int qh = 0; qh < 2; ++qh) {
        const short* qr = qg + (size_t)(q0 + w * 32 + qh * 16 + l15) * DD;
        #pragma unroll
        for (int kk = 0; kk < 8; ++kk)
            qf[qh][kk] = *reinterpret_cast<const bf16x8*>(qr + kk * 32 + lg * 8);
    }

    // staging source offsets (in shorts). Wave w stages K rows 8w..8w+7 and V granule g=w.
    int koff[4], voff[4];
    #pragma unroll
    for (int i = 0; i < 4; ++i) {
        const int j = wu * 4 + i;
        const int row = 2 * j + (lane >> 5);
        koff[i] = row * DD + (((lane & 31) ^ (row & 7)) << 3);
        const int d = (i * 64 + lane) ^ (wu * 2);
        voff[i] = d * MM + wu * 8;
    }

    f32x4 o[2][16];
    #pragma unroll
    for (int qh = 0; qh < 2; ++qh)
        #pragma unroll
        for (int df = 0; df < 16; ++df) o[qh][df] = f32x4{0.f, 0.f, 0.f, 0.f};
    float mrun[2] = {-1e30f, -1e30f};
    float lrun[2] = {0.f, 0.f};
    const int kswz = (l15 & 7) << 4;
    const int sA = ((((lg * 2) & 3) << 4) | l15);
    const int sB = ((((lg * 2 + 1) & 3) << 4) | l15);
    const bool hif = (lg >= 2);

    // prologue: stage tile 0
    #pragma unroll
    for (int i = 0; i < 4; ++i) {
        GLL16(kg + (size_t)m0base * DD + koff[i], &Ks[0][(wu * 4 + i) * 512]);
        GLL16(vT + (size_t)m0base + voff[i], &Vs[0][(wu * 4 + i) * 512]);
    }
    __syncthreads();

    int cur = 0;
    #pragma unroll 1
    for (int t = 0; t < NT; ++t) {
        if (t + 1 < NT) {
            const size_t m0 = (size_t)(m0base + (t + 1) * BK);
            #pragma unroll
            for (int i = 0; i < 4; ++i) {
                GLL16(kg + m0 * DD + koff[i], &Ks[cur ^ 1][(wu * 4 + i) * 512]);
                GLL16(vT + m0 + voff[i], &Vs[cur ^ 1][(wu * 4 + i) * 512]);
            }
        }

        // S^T = K·Q^T : s{f}{qh}, lane holds S[m=f*16+lg*4+r][q=qh*16+l15]
        f32x4 s00 = {0.f,0.f,0.f,0.f}, s01 = {0.f,0.f,0.f,0.f};
        f32x4 s10 = {0.f,0.f,0.f,0.f}, s11 = {0.f,0.f,0.f,0.f};
        const char* kb = (const char*)&Ks[cur][0];
        __builtin_amdgcn_s_setprio(1);
        #pragma unroll
        for (int kk = 0; kk < 8; ++kk) {
            const int cb = (kk * 64 + lg * 16) ^ kswz;
            bf16x8 a0 = *reinterpret_cast<const bf16x8*>(kb + l15 * 512 + cb);
            bf16x8 a1 = *reinterpret_cast<const bf16x8*>(kb + (16 + l15) * 512 + cb);
            s00 = __builtin_amdgcn_mfma_f32_16x16x32_bf16(a0, qf[0][kk], s00, 0, 0, 0);
            s01 = __builtin_amdgcn_mfma_f32_16x16x32_bf16(a0, qf[1][kk], s01, 0, 0, 0);
            s10 = __builtin_amdgcn_mfma_f32_16x16x32_bf16(a1, qf[0][kk], s10, 0, 0, 0);
            s11 = __builtin_amdgcn_mfma_f32_16x16x32_bf16(a1, qf[1][kk], s11, 0, 0, 0);
        }
        __builtin_amdgcn_s_setprio(0);

        // tile max per q (q = l15): in-lane over 8, then across lg groups
        float mx0, mx1;
        {
            float a = fmaxf(fmaxf(s00[0], s00[1]), fmaxf(s00[2], s00[3]));
            float b = fmaxf(fmaxf(s10[0], s10[1]), fmaxf(s10[2], s10[3]));
            float m = fmaxf(a, b);
            m = fmaxf(m, __shfl_xor(m, 16));
            m = fmaxf(m, __shfl_xor(m, 32));
            mx0 = m;
        }
        {
            float a = fmaxf(fmaxf(s01[0], s01[1]), fmaxf(s01[2], s01[3]));
            float b = fmaxf(fmaxf(s11[0], s11[1]), fmaxf(s11[2], s11[3]));
            float m = fmaxf(a, b);
            m = fmaxf(m, __shfl_xor(m, 16));
            m = fmaxf(m, __shfl_xor(m, 32));
            mx1 = m;
        }
        // defer-max (THR = 11.5 in log2 domain); rescale is lane-local (q=l15)
        const bool trig = (mx0 > mrun[0] + 11.5f) || (mx1 > mrun[1] + 11.5f);
        if (__any(trig)) {
            const float mn0 = fmaxf(mrun[0], mx0);
            const float mn1 = fmaxf(mrun[1], mx1);
            const float al0 = __builtin_amdgcn_exp2f(mrun[0] - mn0);
            const float al1 = __builtin_amdgcn_exp2f(mrun[1] - mn1);
            mrun[0] = mn0; mrun[1] = mn1;
            lrun[0] *= al0; lrun[1] *= al1;
            #pragma unroll
            for (int df = 0; df < 16; ++df) {
                #pragma unroll
                for (int r = 0; r < 4; ++r) { o[0][df][r] *= al0; o[1][df][r] *= al1; }
            }
        }

        // P = exp2(S - m); pack to bf16 pairs; redistribute across lg via shfl
        bf16x8 pb0, pb1;
        {
            float p0 = __builtin_amdgcn_exp2f(s00[0] - mrun[0]);
            float p1 = __builtin_amdgcn_exp2f(s00[1] - mrun[0]);
            float p2 = __builtin_amdgcn_exp2f(s00[2] - mrun[0]);
            float p3 = __builtin_amdgcn_exp2f(s00[3] - mrun[0]);
            float p4 = __builtin_amdgcn_exp2f(s10[0] - mrun[0]);
            float p5 = __builtin_amdgcn_exp2f(s10[1] - mrun[0]);
            float p6 = __builtin_amdgcn_exp2f(s10[2] - mrun[0]);
            float p7 = __builtin_amdgcn_exp2f(s10[3] - mrun[0]);
            float rs = ((p0 + p1) + (p2 + p3)) + ((p4 + p5) + (p6 + p7));
            rs += __shfl_xor(rs, 16);
            rs += __shfl_xor(rs, 32);
            lrun[0] += rs;
            u32 pk0 = cvtpk(p0, p1), pk1 = cvtpk(p2, p3);
            u32 pk2 = cvtpk(p4, p5), pk3 = cvtpk(p6, p7);
            u32 b0 = hif ? (u32)__shfl((int)pk2, sA) : (u32)__shfl((int)pk0, sA);
            u32 g00 = (u32)__shfl((int)pk0, sA), g20 = (u32)__shfl((int)pk2, sA);
            u32 g01 = (u32)__shfl((int)pk1, sA), g21 = (u32)__shfl((int)pk3, sA);
            u32 g02 = (u32)__shfl((int)pk0, sB), g22 = (u32)__shfl((int)pk2, sB);
            u32 g03 = (u32)__shfl((int)pk1, sB), g23 = (u32)__shfl((int)pk3, sB);
            u32x4 bb;
            bb[0] = hif ? g20 : g00;
            bb[1] = hif ? g21 : g01;
            bb[2] = hif ? g22 : g02;
            bb[3] = hif ? g23 : g03;
            (void)b0;
            pb0 = __builtin_bit_cast(bf16x8, bb);
        }
        {
            float p0 = __builtin_amdgcn_exp2f(s01[0] - mrun[1]);
            float p1 = __builtin_amdgcn_exp2f(s01[1] - mrun[1]);
            float p2 = __builtin_amdgcn_exp2f(s01[2] - mrun[1]);
            float p3 = __builtin_amdgcn_exp2f(s01[3] - mrun[1]);
            float p4 = __builtin_amdgcn_exp2f(s11[0] - mrun[1]);
            float p5 = __builtin_amdgcn_exp2f(s11[1] - mrun[1]);
            float p6 = __builtin_amdgcn_exp2f(s11[2] - mrun[1]);
            float p7 = __builtin_amdgcn_exp2f(s11[3] - mrun[1]);
            float rs = ((p0 + p1) + (p2 + p3)) + ((p4 + p5) + (p6 + p7));
            rs += __shfl_xor(rs, 16);
            rs += __shfl_xor(rs, 32);
            lrun[1] += rs;
            u32 pk0 = cvtpk(p0, p1), pk1 = cvtpk(p2, p3);
            u32 pk2 = cvtpk(p4, p5), pk3 = cvtpk(p6, p7);
            u32 g00 = (u32)__shfl((int)pk0, sA), g20 = (u32)__shfl((int)pk2, sA);
            u32 g01 = (u32)__shfl((int)pk1, sA), g21 = (u32)__shfl((int)pk3, sA);
            u32 g02 = (u32)__shfl((int)pk0, sB), g22 = (u32)__shfl((int)pk2, sB);
            u32 g03 = (u32)__shfl((int)pk1, sB), g23 = (u32)__shfl((int)pk3, sB);
            u32x4 bb;
            bb[0] = hif ? g20 : g00;
            bb[1] = hif ? g21 : g01;
            bb[2] = hif ? g22 : g02;
            bb[3] = hif ? g23 : g03;
            pb1 = __builtin_bit_cast(bf16x8, bb);
        }

        // O^T += V^T · P : lane holds O[d=df*16+lg*4+r][q=qh*16+l15]
        const char* vb = (const char*)&Vs[cur][0];
        __builtin_amdgcn_s_setprio(1);
        #pragma unroll
        for (int df = 0; df < 16; ++df) {
            bf16x8 av = *reinterpret_cast<const bf16x8*>(
                vb + lg * 4096 + (((df * 16 + l15) ^ (lg * 2)) << 4));
            o[0][df] = __builtin_amdgcn_mfma_f32_16x16x32_bf16(av, pb0, o[0][df], 0, 0, 0);
            o[1][df] = __builtin_amdgcn_mfma_f32_16x16x32_bf16(av, pb1, o[1][df], 0, 0, 0);
        }
        __builtin_amdgcn_s_setprio(0);

        __syncthreads();
        cur ^= 1;
    }

    // epilogue: transpose O^T -> O via per-wave LDS patch, coalesced partial write
    float* tp = &Tp[wu][0];
    #pragma unroll
    for (int qh = 0; qh < 2; ++qh) {
        #pragma unroll
        for (int df = 0; df < 16; ++df) {
            *reinterpret_cast<f32x4*>(&tp[l15 * 20 + lg * 4]) = o[qh][df];
            asm volatile("s_waitcnt lgkmcnt(0)" ::: "memory");
            f32x4 v = *reinterpret_cast<const f32x4*>(&tp[(lane >> 2) * 20 + (lane & 3) * 4]);
            const int qgl = q0 + w * 32 + qh * 16 + (lane >> 2);
            *reinterpret_cast<f32x4*>(&outp[((size_t)p * NN + qgl) * DD + df * 16 + (lane & 3) * 4]) = v;
            asm volatile("s_waitcnt lgkmcnt(0)" ::: "memory");
        }
    }
    if (lg == 0) {
        #pragma unroll
        for (int qh = 0; qh < 2; ++qh) {
            statm[(size_t)p * NN + q0 + w * 32 + qh * 16 + l15] = mrun[qh];
            statl[(size_t)p * NN + q0 + w * 32 + qh * 16 + l15] = lrun[qh];
        }
    }
}

// ---------------- combine partials (exp2 domain) ----------------
__global__ __launch_bounds__(256) void combine_kernel(
    const float* __restrict__ outp, const float* __restrict__ statm,
    const float* __restrict__ statl, float* __restrict__ out)
{
    const int q = blockIdx.x;
    const int d = threadIdx.x;
    float mv[NPART], lv[NPART];
    float mM = -1e30f;
    #pragma unroll
    for (int p = 0; p < NPART; ++p) {
        mv[p] = statm[(size_t)p * NN + q];
        lv[p] = statl[(size_t)p * NN + q];
        mM = fmaxf(mM, mv[p]);
    }
    float L = 0.f, acc = 0.f;
    #pragma unroll
    for (int p = 0; p < NPART; ++p) {
        const float wgt = exp2f(mv[p] - mM);
        L += wgt * lv[p];
        acc += wgt * outp[((size_t)p * NN + q) * DD + d];
    }
    out[(size_t)q * DD + d] = acc / L;
}

extern "C" void kernel_launch(void* const* d_in, const int* in_sizes, int n_in,
                              void* d_out, int out_size, void* d_ws, size_t ws_size,
                              hipStream_t stream) {
    const float* xq  = (const float*)d_in[0];
    const float* xkv = (const float*)d_in[1];
    const float* Wq  = (const float*)d_in[2];
    const float* bq  = (const float*)d_in[3];
    const float* Wk  = (const float*)d_in[4];
    const float* bk  = (const float*)d_in[5];
    const float* Wv  = (const float*)d_in[6];
    const float* bv  = (const float*)d_in[7];
    float* out = (float*)d_out;

    char* ws = (char*)d_ws;
    short* qb  = (short*)(ws);                       // 4 MiB  bf16 q (pre-scaled)
    short* kb  = (short*)(ws + ((size_t)4 << 20));   // 4 MiB  bf16 k
    short* vTb = (short*)(ws + ((size_t)8 << 20));   // 4 MiB  bf16 v^T [D][M]
    float* outp = (float*)(ws + ((size_t)12 << 20)); // 64 MiB partials [NPART][N][D]
    float* sm = (float*)(ws + ((size_t)12 << 20) + (size_t)NPART * NN * DD * 4);
    float* sl = sm + (size_t)NPART * NN;

    proj_kernel<<<1536, 256, 0, stream>>>(xq, xkv, Wq, bq, Wk, bk, Wv, bv, qb, kb, vTb);
    attn_kernel<<<512, 256, 0, stream>>>(qb, kb, vTb, outp, sm, sl);
    combine_kernel<<<8192, 256, 0, stream>>>(outp, sm, sl, out);
}